// Round 7
// baseline (404.722 us; speedup 1.0000x reference)
//
#include <hip/hip_runtime.h>
#include <hip/hip_bf16.h>
#include <math.h>

typedef __bf16 bf16x8 __attribute__((ext_vector_type(8)));
typedef __bf16 bf16x4 __attribute__((ext_vector_type(4)));
typedef float  f32x4  __attribute__((ext_vector_type(4)));

#define MFMA16(a, b, c) __builtin_amdgcn_mfma_f32_16x16x32_bf16((a), (b), (c), 0, 0, 0)

// async global->LDS, 16B per lane. LDS dest must be wave-uniform base + lane*16.
__device__ __forceinline__ void gl16(const void* g, void* l) {
  __builtin_amdgcn_global_load_lds(
      (const __attribute__((address_space(1))) unsigned int*)g,
      (__attribute__((address_space(3))) unsigned int*)l, 16, 0, 0);
}

// ---------------------------------------------------------------------------
// Fused fp32 -> bf16 cast of all 5 tensors (segment bounds are block-uniform).
// ---------------------------------------------------------------------------
__global__ __launch_bounds__(256) void cast_all(
    const float* __restrict__ x, const float* __restrict__ wqkv,
    const float* __restrict__ wout, const float* __restrict__ w1,
    const float* __restrict__ w2, __bf16* __restrict__ xb,
    __bf16* __restrict__ wqkvb, __bf16* __restrict__ woutb,
    __bf16* __restrict__ w1b, __bf16* __restrict__ w2b) {
  const long i = ((long)blockIdx.x * 256 + threadIdx.x) * 4;
  const float* src;
  __bf16* dst;
  long off;
  if (i < 4194304L) { src = x; dst = xb; off = i; }
  else if (i < 7340032L) { src = wqkv; dst = wqkvb; off = i - 4194304L; }
  else if (i < 8388608L) { src = wout; dst = woutb; off = i - 7340032L; }
  else if (i < 12582912L) { src = w1; dst = w1b; off = i - 8388608L; }
  else { src = w2; dst = w2b; off = i - 12582912L; }
  const float4 f = *(const float4*)(src + off);
  bf16x4 o = {(__bf16)f.x, (__bf16)f.y, (__bf16)f.z, (__bf16)f.w};
  *(bf16x4*)(dst + off) = o;
}

// ---------------------------------------------------------------------------
// 256x256-tile bf16 GEMM (L3-traffic-optimized: staging factor 1/128 vs 1/64
// for 128x128). 512 thr = 8 waves in 2(m)x4(n), each wave 128x64, BK=32.
// MODE 0: QKV scatter (q pre-scaled 0.125*log2e; k row-major; V^T tile-blocked)
// MODE 2: outB = bf16(gelu_exact(gemm + bias))
// ---------------------------------------------------------------------------
template <int MODE>
__global__ __launch_bounds__(512, 2) void gemm256(
    const __bf16* __restrict__ A, const __bf16* __restrict__ Bw,
    const float* __restrict__ bias, __bf16* __restrict__ outB,
    int M, int N, int K) {
  __shared__ __bf16 As[256 * 32];
  __shared__ __bf16 Bs[256 * 32];
  const int tid = threadIdx.x;
  const int wave = tid >> 6, lane = tid & 63;
  const int quad = lane >> 4, l16 = lane & 15;
  const int wm = (wave >> 2) * 128, wn = (wave & 3) * 64;
  const long bm = (long)blockIdx.y * 256, bn = (long)blockIdx.x * 256;
  const int r0 = tid >> 2;          // staging row 0..127
  const int c0 = (tid & 3) * 8;
  const __bf16* Ag = A + (bm + r0) * (long)K + c0;
  const __bf16* Bg = Bw + (bn + r0) * (long)K + c0;

  f32x4 acc[8][4] = {};

  for (int k0 = 0; k0 < K; k0 += 32) {
    __syncthreads();
    gl16(Ag + k0, &As[tid * 8]);
    gl16(Ag + 128 * (long)K + k0, &As[4096 + tid * 8]);
    gl16(Bg + k0, &Bs[tid * 8]);
    gl16(Bg + 128 * (long)K + k0, &Bs[4096 + tid * 8]);
    __syncthreads();

    bf16x8 af[8], bfr[4];
#pragma unroll
    for (int mt = 0; mt < 8; mt++)
      af[mt] = *(const bf16x8*)&As[(wm + mt * 16 + l16) * 32 + quad * 8];
#pragma unroll
    for (int nt = 0; nt < 4; nt++)
      bfr[nt] = *(const bf16x8*)&Bs[(wn + nt * 16 + l16) * 32 + quad * 8];
#pragma unroll
    for (int nt = 0; nt < 4; nt++)
#pragma unroll
      for (int mt = 0; mt < 8; mt++)
        acc[mt][nt] = MFMA16(af[mt], bfr[nt], acc[mt][nt]);
  }

#pragma unroll
  for (int mt = 0; mt < 8; mt++) {
#pragma unroll
    for (int nt = 0; nt < 4; nt++) {
#pragma unroll
      for (int r = 0; r < 4; r++) {
        const int row = (int)bm + wm + mt * 16 + quad * 4 + r;
        const int col = (int)bn + wn + nt * 16 + l16;
        float v = acc[mt][nt][r] + bias[col];
        if (MODE == 0) {
          const int b = row >> 11, s = row & 2047;
          const int h = col / 192, rem = col - h * 192;
          const int seg = rem >> 6, d = rem & 63;
          const int hb = h * 2 + b;
          if (seg == 0) {
            v *= 0.180336880111113704f;  // 1/sqrt(64) * log2(e)
            outB[((long)hb * 2048 + s) * 64 + d] = (__bf16)v;
          } else if (seg == 1) {
            outB[4194304L + ((long)hb * 2048 + s) * 64 + d] = (__bf16)v;
          } else {
            const int t = s >> 6, kp = s & 63;
            outB[2 * 4194304L + (((long)hb * 32 + t) * 64 + d) * 64 + kp] = (__bf16)v;
          }
        } else {
          const float g = 0.5f * v * (1.0f + erff(v * 0.70710678118654752f));
          outB[(long)row * N + col] = (__bf16)g;
        }
      }
    }
  }
}

// ---------------------------------------------------------------------------
// 256x256-tile split-K GEMM: grid (N/256, M/256, 4). Stores bf16 partial
// (no bias) at Pbase + offs[z]. Used for FFN2 (K=4096 -> 4x1024).
// ---------------------------------------------------------------------------
__global__ __launch_bounds__(512, 2) void gemm256_split(
    const __bf16* __restrict__ A, const __bf16* __restrict__ Bw,
    __bf16* __restrict__ Pbase, const long4 offs, int N, int K, int splitK) {
  __shared__ __bf16 As[256 * 32];
  __shared__ __bf16 Bs[256 * 32];
  const int tid = threadIdx.x;
  const int wave = tid >> 6, lane = tid & 63;
  const int quad = lane >> 4, l16 = lane & 15;
  const int wm = (wave >> 2) * 128, wn = (wave & 3) * 64;
  const long bm = (long)blockIdx.y * 256, bn = (long)blockIdx.x * 256;
  const int z = blockIdx.z;
  const long kb = (long)z * splitK;
  const int r0 = tid >> 2;
  const int c0 = (tid & 3) * 8;
  const __bf16* Ag = A + (bm + r0) * (long)K + c0 + kb;
  const __bf16* Bg = Bw + (bn + r0) * (long)K + c0 + kb;

  f32x4 acc[8][4] = {};

  for (int k0 = 0; k0 < splitK; k0 += 32) {
    __syncthreads();
    gl16(Ag + k0, &As[tid * 8]);
    gl16(Ag + 128 * (long)K + k0, &As[4096 + tid * 8]);
    gl16(Bg + k0, &Bs[tid * 8]);
    gl16(Bg + 128 * (long)K + k0, &Bs[4096 + tid * 8]);
    __syncthreads();

    bf16x8 af[8], bfr[4];
#pragma unroll
    for (int mt = 0; mt < 8; mt++)
      af[mt] = *(const bf16x8*)&As[(wm + mt * 16 + l16) * 32 + quad * 8];
#pragma unroll
    for (int nt = 0; nt < 4; nt++)
      bfr[nt] = *(const bf16x8*)&Bs[(wn + nt * 16 + l16) * 32 + quad * 8];
#pragma unroll
    for (int nt = 0; nt < 4; nt++)
#pragma unroll
      for (int mt = 0; mt < 8; mt++)
        acc[mt][nt] = MFMA16(af[mt], bfr[nt], acc[mt][nt]);
  }

  const long po = (z == 0) ? offs.x : (z == 1) ? offs.y : (z == 2) ? offs.z : offs.w;
#pragma unroll
  for (int mt = 0; mt < 8; mt++)
#pragma unroll
    for (int nt = 0; nt < 4; nt++)
#pragma unroll
      for (int r = 0; r < 4; r++) {
        const int row = (int)bm + wm + mt * 16 + quad * 4 + r;
        const int col = (int)bn + wn + nt * 16 + l16;
        Pbase[po + (long)row * N + col] = (__bf16)acc[mt][nt][r];
      }
}

// ---------------------------------------------------------------------------
// 128x128-tile split-K GEMM (out-proj: K=1024 -> 4x256, 1024 blocks).
// ---------------------------------------------------------------------------
__global__ __launch_bounds__(256, 2) void gemm_split(
    const __bf16* __restrict__ A, const __bf16* __restrict__ Bw,
    __bf16* __restrict__ Pbase, const long4 offs, int N, int K, int splitK) {
  __shared__ __bf16 As[128 * 32];
  __shared__ __bf16 Bs[128 * 32];
  const int tid = threadIdx.x;
  const int wave = tid >> 6, lane = tid & 63;
  const int quad = lane >> 4, l16 = lane & 15;
  const int wm = (wave >> 1) * 64, wn = (wave & 1) * 64;
  const long bm = (long)blockIdx.y * 128, bn = (long)blockIdx.x * 128;
  const int z = blockIdx.z;
  const long kb = (long)z * splitK;
  const int r0 = tid >> 2;
  const int c0 = (tid & 3) * 8;
  const __bf16* Ag = A + (bm + r0) * (long)K + c0 + kb;
  const __bf16* Bg = Bw + (bn + r0) * (long)K + c0 + kb;

  f32x4 acc[4][4] = {};

  for (int k0 = 0; k0 < splitK; k0 += 32) {
    __syncthreads();
    gl16(Ag + k0, &As[tid * 8]);
    gl16(Ag + 64 * (long)K + k0, &As[2048 + tid * 8]);
    gl16(Bg + k0, &Bs[tid * 8]);
    gl16(Bg + 64 * (long)K + k0, &Bs[2048 + tid * 8]);
    __syncthreads();

    bf16x8 af[4], bfr[4];
#pragma unroll
    for (int mt = 0; mt < 4; mt++)
      af[mt] = *(const bf16x8*)&As[(wm + mt * 16 + l16) * 32 + quad * 8];
#pragma unroll
    for (int nt = 0; nt < 4; nt++)
      bfr[nt] = *(const bf16x8*)&Bs[(wn + nt * 16 + l16) * 32 + quad * 8];
#pragma unroll
    for (int nt = 0; nt < 4; nt++)
#pragma unroll
      for (int mt = 0; mt < 4; mt++)
        acc[mt][nt] = MFMA16(af[mt], bfr[nt], acc[mt][nt]);
  }

  const long po = (z == 0) ? offs.x : (z == 1) ? offs.y : (z == 2) ? offs.z : offs.w;
#pragma unroll
  for (int mt = 0; mt < 4; mt++)
#pragma unroll
    for (int nt = 0; nt < 4; nt++)
#pragma unroll
      for (int r = 0; r < 4; r++) {
        const int row = (int)bm + wm + mt * 16 + quad * 4 + r;
        const int col = (int)bn + wn + nt * 16 + l16;
        Pbase[po + (long)row * N + col] = (__bf16)acc[mt][nt][r];
      }
}

// ---------------------------------------------------------------------------
// Fused: sum 4 bf16 split-K partials + bias + residual, then LayerNorm.
// ---------------------------------------------------------------------------
template <int WB>
__global__ __launch_bounds__(256) void reduce_ln(
    const __bf16* __restrict__ Pbase, const long4 offs,
    const float* __restrict__ resid, const float* __restrict__ bias,
    const float* __restrict__ g, const float* __restrict__ be,
    float* __restrict__ outF, __bf16* __restrict__ outB) {
  const int tid = threadIdx.x;
  const long row = blockIdx.x;
  const int c = tid * 4;
  float4 v = ((const float4*)(resid + row * 1024))[tid];
  const float4 bb = ((const float4*)bias)[tid];
  v.x += bb.x; v.y += bb.y; v.z += bb.z; v.w += bb.w;
  const long lo[4] = {offs.x, offs.y, offs.z, offs.w};
#pragma unroll
  for (int s = 0; s < 4; s++) {
    const bf16x4 p = *(const bf16x4*)&Pbase[lo[s] + row * 1024 + c];
    v.x += (float)p[0]; v.y += (float)p[1]; v.z += (float)p[2]; v.w += (float)p[3];
  }
  float sum = v.x + v.y + v.z + v.w;
  float sq = v.x * v.x + v.y * v.y + v.z * v.z + v.w * v.w;
#pragma unroll
  for (int m = 32; m >= 1; m >>= 1) {
    sum += __shfl_xor(sum, m);
    sq += __shfl_xor(sq, m);
  }
  __shared__ float red[8];
  const int wave = tid >> 6;
  if ((tid & 63) == 0) {
    red[wave] = sum;
    red[4 + wave] = sq;
  }
  __syncthreads();
  sum = red[0] + red[1] + red[2] + red[3];
  sq = red[4] + red[5] + red[6] + red[7];
  const float mu = sum * (1.f / 1024.f);
  const float var = sq * (1.f / 1024.f) - mu * mu;
  const float rs = rsqrtf(var + 1e-5f);
  const float4 gv = ((const float4*)g)[tid];
  const float4 bv = ((const float4*)be)[tid];
  float4 o;
  o.x = (v.x - mu) * rs * gv.x + bv.x;
  o.y = (v.y - mu) * rs * gv.y + bv.y;
  o.z = (v.z - mu) * rs * gv.z + bv.z;
  o.w = (v.w - mu) * rs * gv.w + bv.w;
  ((float4*)(outF + row * 1024))[tid] = o;
  if (WB) {
    bf16x4 ob = {(__bf16)o.x, (__bf16)o.y, (__bf16)o.z, (__bf16)o.w};
    *(bf16x4*)&outB[row * 1024 + c] = ob;
  }
}

// ---------------------------------------------------------------------------
// Flash attention: LDS-staged K/V tiles, 32 q-rows/wave, XCD-swizzled grid,
// static softmax (exp2 domain). P buffer stride 68 elements: quad groups land
// on distinct bank octets (4-way -> 2-way/free conflicts); reads via 8B-
// aligned b64 pairs.
// ---------------------------------------------------------------------------
__global__ __launch_bounds__(256) void flash_attn(const __bf16* __restrict__ Qb,
                                                  const __bf16* __restrict__ Kb,
                                                  const __bf16* __restrict__ Vtb,
                                                  __bf16* __restrict__ ctx) {
  __shared__ __bf16 KsLo[64 * 32], KsHi[64 * 32];   // K tile, d 0:32 / 32:64
  __shared__ __bf16 VsLo[64 * 32], VsHi[64 * 32];   // V^T tile, key 0:32 / 32:64
  __shared__ __bf16 Pb[4][32 * 68];                 // per-wave P, stride 68
  const int tid = threadIdx.x;
  const int wave = tid >> 6, lane = tid & 63;
  const int quad = lane >> 4, l16 = lane & 15;
  const int n = blockIdx.x;
  const int hb = n & 31;          // same hb -> same (n mod 8) -> same XCD
  const int qblk = n >> 5;
  const int h = hb >> 1, b = hb & 1;
  const __bf16* Q = Qb + (long)hb * 131072;
  const __bf16* K = Kb + (long)hb * 131072;
  const __bf16* Vt = Vtb + (long)hb * 131072;   // [t][d][k'] tiles of 64x64
  const int qr = qblk * 128 + wave * 32;

  bf16x8 q0[2], q1[2];
#pragma unroll
  for (int rb = 0; rb < 2; rb++) {
    q0[rb] = *(const bf16x8*)&Q[(qr + rb * 16 + l16) * 64 + quad * 8];
    q1[rb] = *(const bf16x8*)&Q[(qr + rb * 16 + l16) * 64 + 32 + quad * 8];
  }

  f32x4 o[2][4] = {};
  f32x4 lp[2] = {};

  const int sr = tid >> 2;         // staging row 0..63
  const int sc = (tid & 3) * 8;    // staging col chunk

  for (int kt = 0; kt < 2048; kt += 64) {
    __syncthreads();
    gl16(&K[(kt + sr) * 64 + sc], &KsLo[tid * 8]);
    gl16(&K[(kt + sr) * 64 + 32 + sc], &KsHi[tid * 8]);
    const __bf16* Vtile = Vt + (long)(kt >> 6) * 4096;
    gl16(&Vtile[sr * 64 + sc], &VsLo[tid * 8]);
    gl16(&Vtile[sr * 64 + 32 + sc], &VsHi[tid * 8]);
    __syncthreads();

    // S = Q K^T in exp2 domain
    bf16x8 kf0[4], kf1[4];
#pragma unroll
    for (int nt = 0; nt < 4; nt++) {
      kf0[nt] = *(const bf16x8*)&KsLo[(nt * 16 + l16) * 32 + quad * 8];
      kf1[nt] = *(const bf16x8*)&KsHi[(nt * 16 + l16) * 32 + quad * 8];
    }
    f32x4 s[2][4];
#pragma unroll
    for (int rb = 0; rb < 2; rb++)
#pragma unroll
      for (int nt = 0; nt < 4; nt++) {
        f32x4 z = {};
        z = MFMA16(q0[rb], kf0[nt], z);
        z = MFMA16(q1[rb], kf1[nt], z);
        s[rb][nt] = z;
      }

    // P = exp2(S); per-lane partial row sums
#pragma unroll
    for (int rb = 0; rb < 2; rb++)
#pragma unroll
      for (int nt = 0; nt < 4; nt++)
#pragma unroll
        for (int r = 0; r < 4; r++) {
          const float p = __builtin_amdgcn_exp2f(s[rb][nt][r]);
          s[rb][nt][r] = p;
          lp[rb][r] += p;
        }

    // P: C-layout -> LDS (stride 68) -> A-operand layout (wave-private)
#pragma unroll
    for (int rb = 0; rb < 2; rb++)
#pragma unroll
      for (int nt = 0; nt < 4; nt++)
#pragma unroll
        for (int r = 0; r < 4; r++)
          Pb[wave][(rb * 16 + quad * 4 + r) * 68 + nt * 16 + l16] =
              (__bf16)s[rb][nt][r];

    bf16x8 vf0[4], vf1[4];
#pragma unroll
    for (int nt = 0; nt < 4; nt++) {
      vf0[nt] = *(const bf16x8*)&VsLo[(nt * 16 + l16) * 32 + quad * 8];
      vf1[nt] = *(const bf16x8*)&VsHi[(nt * 16 + l16) * 32 + quad * 8];
    }
#pragma unroll
    for (int rb = 0; rb < 2; rb++) {
      const int pbase = (rb * 16 + l16) * 68;
      const bf16x4 pa0 = *(const bf16x4*)&Pb[wave][pbase + quad * 8];
      const bf16x4 pa1 = *(const bf16x4*)&Pb[wave][pbase + quad * 8 + 4];
      const bf16x4 pb0 = *(const bf16x4*)&Pb[wave][pbase + 32 + quad * 8];
      const bf16x4 pb1 = *(const bf16x4*)&Pb[wave][pbase + 32 + quad * 8 + 4];
      const bf16x8 p0 = __builtin_shufflevector(pa0, pa1, 0, 1, 2, 3, 4, 5, 6, 7);
      const bf16x8 p1 = __builtin_shufflevector(pb0, pb1, 0, 1, 2, 3, 4, 5, 6, 7);
#pragma unroll
      for (int nt = 0; nt < 4; nt++) {
        o[rb][nt] = MFMA16(p0, vf0[nt], o[rb][nt]);
        o[rb][nt] = MFMA16(p1, vf1[nt], o[rb][nt]);
      }
    }
  }

  // final row-sum reduction + ctx write in [b][s][h*64+d] layout
#pragma unroll
  for (int rb = 0; rb < 2; rb++) {
    float inv[4];
#pragma unroll
    for (int r = 0; r < 4; r++) {
      float l = lp[rb][r];
      l += __shfl_xor(l, 1);
      l += __shfl_xor(l, 2);
      l += __shfl_xor(l, 4);
      l += __shfl_xor(l, 8);
      inv[r] = __builtin_amdgcn_rcpf(l);
    }
#pragma unroll
    for (int nt = 0; nt < 4; nt++)
#pragma unroll
      for (int r = 0; r < 4; r++) {
        const int srow = qr + rb * 16 + quad * 4 + r;
        const float val = o[rb][nt][r] * inv[r];
        const int d = nt * 16 + l16;
        ctx[((long)(b * 2048 + srow)) * 1024 + h * 64 + d] = (__bf16)val;
      }
  }
}

// ---------------------------------------------------------------------------
extern "C" void kernel_launch(void* const* d_in, const int* in_sizes, int n_in,
                              void* d_out, int out_size, void* d_ws, size_t ws_size,
                              hipStream_t stream) {
  const float* x     = (const float*)d_in[0];
  const float* w_qkv = (const float*)d_in[1];
  const float* b_qkv = (const float*)d_in[2];
  const float* w_out = (const float*)d_in[3];
  const float* b_out = (const float*)d_in[4];
  const float* g1    = (const float*)d_in[5];
  const float* be1   = (const float*)d_in[6];
  const float* g2    = (const float*)d_in[7];
  const float* be2   = (const float*)d_in[8];
  const float* w1    = (const float*)d_in[9];
  const float* bf1   = (const float*)d_in[10];
  const float* w2    = (const float*)d_in[11];
  const float* bf2   = (const float*)d_in[12];
  float* out = (float*)d_out;

  // ---- workspace layout (MB offsets), 88 MB, lifetime-checked (round 6) ----
  //  0- 6 wqkvb | 6- 8 woutb | 8-16 w1b | 16-24 w2b | 24-32 xb
  // 32-56 qkvb | 56-64 ctxb | 64-80 res1 (f32) | 80-88 x1b
  // P1 (out-proj partials, 4x8 MB): {24,32,40,48}   (xb,qkvb dead)
  // hb (FFN1 out, 32 MB): 24-56                      (P1 dead)
  // P2 (FFN2 partials, 4x8 MB): {0,8,56,80}          (wqkvb/woutb,w1b,ctxb,x1b dead)
  char* ws = (char*)d_ws;
  const long MB = 1024L * 1024;
  __bf16* wsb   = (__bf16*)ws;
  __bf16* wqkvb = (__bf16*)(ws + 0 * MB);
  __bf16* woutb = (__bf16*)(ws + 6 * MB);
  __bf16* w1b   = (__bf16*)(ws + 8 * MB);
  __bf16* w2b   = (__bf16*)(ws + 16 * MB);
  __bf16* xb    = (__bf16*)(ws + 24 * MB);
  __bf16* qkvb  = (__bf16*)(ws + 32 * MB);
  __bf16* ctxb  = (__bf16*)(ws + 56 * MB);
  float*  res1  = (float*)(ws + 64 * MB);
  __bf16* x1b   = (__bf16*)(ws + 80 * MB);
  __bf16* hb    = (__bf16*)(ws + 24 * MB);

  const long4 offs_op = {24 * 524288L, 32 * 524288L, 40 * 524288L, 48 * 524288L};
  const long4 offs_f2 = {0 * 524288L, 8 * 524288L, 56 * 524288L, 80 * 524288L};

  // fused bf16 casts (16M elements)
  cast_all<<<16384, 256, 0, stream>>>(x, w_qkv, w_out, w1, w2,
                                      xb, wqkvb, woutb, w1b, w2b);

  // QKV projection (256x256 tiles) -> q, k, tile-blocked V^T
  gemm256<0><<<dim3(12, 16), 512, 0, stream>>>(xb, wqkvb, b_qkv, qkvb,
                                               4096, 3072, 1024);
  // attention
  flash_attn<<<512, 256, 0, stream>>>(qkvb, qkvb + 4194304,
                                      qkvb + 2 * 4194304, ctxb);
  // out projection, split-K=4 (128x128 tiles, 1024 blocks)
  gemm_split<<<dim3(8, 32, 4), 256, 0, stream>>>(ctxb, woutb, wsb, offs_op,
                                                 1024, 1024, 256);
  // fused: sum partials + b_out + x, LN1 -> res1 fp32 + x1b bf16
  reduce_ln<1><<<4096, 256, 0, stream>>>(wsb, offs_op, x, b_out, g1, be1,
                                         res1, x1b);
  // FFN1 + exact GELU (256x256 tiles)
  gemm256<2><<<dim3(16, 16), 512, 0, stream>>>(x1b, w1b, bf1, hb,
                                               4096, 4096, 1024);
  // FFN2, split-K=4 (256x256 tiles, 256 blocks)
  gemm256_split<<<dim3(4, 16, 4), 512, 0, stream>>>(hb, w2b, wsb, offs_f2,
                                                    1024, 4096, 1024);
  // fused: sum partials + bf2 + res1, LN2 -> out
  reduce_ln<0><<<4096, 256, 0, stream>>>(wsb, offs_f2, res1, bf2, g2, be2,
                                         out, nullptr);
}

// Round 8
// 357.125 us; speedup vs baseline: 1.1333x; 1.1333x over previous
//
#include <hip/hip_runtime.h>
#include <hip/hip_bf16.h>
#include <math.h>

typedef __bf16 bf16x8 __attribute__((ext_vector_type(8)));
typedef __bf16 bf16x4 __attribute__((ext_vector_type(4)));
typedef float  f32x4  __attribute__((ext_vector_type(4)));

#define MFMA16(a, b, c) __builtin_amdgcn_mfma_f32_16x16x32_bf16((a), (b), (c), 0, 0, 0)

// async global->LDS, 16B per lane. LDS dest must be wave-uniform base + lane*16.
__device__ __forceinline__ void gl16(const void* g, void* l) {
  __builtin_amdgcn_global_load_lds(
      (const __attribute__((address_space(1))) unsigned int*)g,
      (__attribute__((address_space(3))) unsigned int*)l, 16, 0, 0);
}

// ---------------------------------------------------------------------------
// Fused fp32 -> bf16 cast of all 5 tensors (segment bounds are block-uniform).
// ---------------------------------------------------------------------------
__global__ __launch_bounds__(256) void cast_all(
    const float* __restrict__ x, const float* __restrict__ wqkv,
    const float* __restrict__ wout, const float* __restrict__ w1,
    const float* __restrict__ w2, __bf16* __restrict__ xb,
    __bf16* __restrict__ wqkvb, __bf16* __restrict__ woutb,
    __bf16* __restrict__ w1b, __bf16* __restrict__ w2b) {
  const long i = ((long)blockIdx.x * 256 + threadIdx.x) * 4;
  const float* src;
  __bf16* dst;
  long off;
  if (i < 4194304L) { src = x; dst = xb; off = i; }
  else if (i < 7340032L) { src = wqkv; dst = wqkvb; off = i - 4194304L; }
  else if (i < 8388608L) { src = wout; dst = woutb; off = i - 7340032L; }
  else if (i < 12582912L) { src = w1; dst = w1b; off = i - 8388608L; }
  else { src = w2; dst = w2b; off = i - 12582912L; }
  const float4 f = *(const float4*)(src + off);
  bf16x4 o = {(__bf16)f.x, (__bf16)f.y, (__bf16)f.z, (__bf16)f.w};
  *(bf16x4*)(dst + off) = o;
}

// ---------------------------------------------------------------------------
// 128x128-tile bf16 GEMM, BK=64 K-loop (half the barrier drains of BK=32).
// LDS: two 32-col half-buffers per operand (keeps the proven 64B-row staging
// and fragment pattern). 256 thr, 4 waves 2x2, 32 MFMA/iter.
// MODE 0: QKV scatter (q pre-scaled 0.125*log2e; k row-major; V^T tile-blocked)
// MODE 2: outB = bf16(gelu_exact(gemm + bias))
// ---------------------------------------------------------------------------
template <int MODE>
__global__ __launch_bounds__(256, 2) void gemm_bt(
    const __bf16* __restrict__ A, const __bf16* __restrict__ Bw,
    const float* __restrict__ bias, __bf16* __restrict__ outB,
    int M, int N, int K) {
  __shared__ __bf16 AsL[128 * 32], AsH[128 * 32];
  __shared__ __bf16 BsL[128 * 32], BsH[128 * 32];
  const int tid = threadIdx.x;
  const int wave = tid >> 6, lane = tid & 63;
  const int quad = lane >> 4, l16 = lane & 15;
  const int wm = (wave >> 1) * 64, wn = (wave & 1) * 64;
  const long bm = (long)blockIdx.y * 128, bn = (long)blockIdx.x * 128;
  const int r0 = tid >> 2;          // staging row (4 thr x 16B cover one 32-col half)
  const int c0 = (tid & 3) * 8;
  const __bf16* Ag = A + (bm + r0) * (long)K + c0;
  const __bf16* Bg = Bw + (bn + r0) * (long)K + c0;

  f32x4 acc[4][4] = {};

  for (int k0 = 0; k0 < K; k0 += 64) {
    __syncthreads();
    gl16(Ag + k0, &AsL[tid * 8]);
    gl16(Ag + 64 * (long)K + k0, &AsL[2048 + tid * 8]);
    gl16(Ag + k0 + 32, &AsH[tid * 8]);
    gl16(Ag + 64 * (long)K + k0 + 32, &AsH[2048 + tid * 8]);
    gl16(Bg + k0, &BsL[tid * 8]);
    gl16(Bg + 64 * (long)K + k0, &BsL[2048 + tid * 8]);
    gl16(Bg + k0 + 32, &BsH[tid * 8]);
    gl16(Bg + 64 * (long)K + k0 + 32, &BsH[2048 + tid * 8]);
    __syncthreads();

    bf16x8 afL[4], afH[4], bfL[4], bfH[4];
#pragma unroll
    for (int mt = 0; mt < 4; mt++) {
      afL[mt] = *(const bf16x8*)&AsL[(wm + mt * 16 + l16) * 32 + quad * 8];
      afH[mt] = *(const bf16x8*)&AsH[(wm + mt * 16 + l16) * 32 + quad * 8];
    }
#pragma unroll
    for (int nt = 0; nt < 4; nt++) {
      bfL[nt] = *(const bf16x8*)&BsL[(wn + nt * 16 + l16) * 32 + quad * 8];
      bfH[nt] = *(const bf16x8*)&BsH[(wn + nt * 16 + l16) * 32 + quad * 8];
    }
#pragma unroll
    for (int nt = 0; nt < 4; nt++)
#pragma unroll
      for (int mt = 0; mt < 4; mt++) {
        acc[mt][nt] = MFMA16(afL[mt], bfL[nt], acc[mt][nt]);
        acc[mt][nt] = MFMA16(afH[mt], bfH[nt], acc[mt][nt]);
      }
  }

#pragma unroll
  for (int mt = 0; mt < 4; mt++) {
#pragma unroll
    for (int nt = 0; nt < 4; nt++) {
#pragma unroll
      for (int r = 0; r < 4; r++) {
        const int row = (int)bm + wm + mt * 16 + quad * 4 + r;
        const int col = (int)bn + wn + nt * 16 + l16;
        float v = acc[mt][nt][r] + bias[col];
        if (MODE == 0) {
          const int b = row >> 11, s = row & 2047;
          const int h = col / 192, rem = col - h * 192;
          const int seg = rem >> 6, d = rem & 63;
          const int hb = h * 2 + b;
          if (seg == 0) {
            v *= 0.180336880111113704f;  // 1/sqrt(64) * log2(e)
            outB[((long)hb * 2048 + s) * 64 + d] = (__bf16)v;
          } else if (seg == 1) {
            outB[4194304L + ((long)hb * 2048 + s) * 64 + d] = (__bf16)v;
          } else {
            const int t = s >> 6, kp = s & 63;
            outB[2 * 4194304L + (((long)hb * 32 + t) * 64 + d) * 64 + kp] = (__bf16)v;
          }
        } else {
          const float g = 0.5f * v * (1.0f + erff(v * 0.70710678118654752f));
          outB[(long)row * N + col] = (__bf16)g;
        }
      }
    }
  }
}

// ---------------------------------------------------------------------------
// 128x128-tile split-K GEMM, BK=64. grid (N/128, M/128, 4); bf16 partial
// (no bias) at Pbase + offs[z].
// ---------------------------------------------------------------------------
__global__ __launch_bounds__(256, 2) void gemm_split(
    const __bf16* __restrict__ A, const __bf16* __restrict__ Bw,
    __bf16* __restrict__ Pbase, const long4 offs, int N, int K, int splitK) {
  __shared__ __bf16 AsL[128 * 32], AsH[128 * 32];
  __shared__ __bf16 BsL[128 * 32], BsH[128 * 32];
  const int tid = threadIdx.x;
  const int wave = tid >> 6, lane = tid & 63;
  const int quad = lane >> 4, l16 = lane & 15;
  const int wm = (wave >> 1) * 64, wn = (wave & 1) * 64;
  const long bm = (long)blockIdx.y * 128, bn = (long)blockIdx.x * 128;
  const int z = blockIdx.z;
  const long kb = (long)z * splitK;
  const int r0 = tid >> 2;
  const int c0 = (tid & 3) * 8;
  const __bf16* Ag = A + (bm + r0) * (long)K + c0 + kb;
  const __bf16* Bg = Bw + (bn + r0) * (long)K + c0 + kb;

  f32x4 acc[4][4] = {};

  for (int k0 = 0; k0 < splitK; k0 += 64) {
    __syncthreads();
    gl16(Ag + k0, &AsL[tid * 8]);
    gl16(Ag + 64 * (long)K + k0, &AsL[2048 + tid * 8]);
    gl16(Ag + k0 + 32, &AsH[tid * 8]);
    gl16(Ag + 64 * (long)K + k0 + 32, &AsH[2048 + tid * 8]);
    gl16(Bg + k0, &BsL[tid * 8]);
    gl16(Bg + 64 * (long)K + k0, &BsL[2048 + tid * 8]);
    gl16(Bg + k0 + 32, &BsH[tid * 8]);
    gl16(Bg + 64 * (long)K + k0 + 32, &BsH[2048 + tid * 8]);
    __syncthreads();

    bf16x8 afL[4], afH[4], bfL[4], bfH[4];
#pragma unroll
    for (int mt = 0; mt < 4; mt++) {
      afL[mt] = *(const bf16x8*)&AsL[(wm + mt * 16 + l16) * 32 + quad * 8];
      afH[mt] = *(const bf16x8*)&AsH[(wm + mt * 16 + l16) * 32 + quad * 8];
    }
#pragma unroll
    for (int nt = 0; nt < 4; nt++) {
      bfL[nt] = *(const bf16x8*)&BsL[(wn + nt * 16 + l16) * 32 + quad * 8];
      bfH[nt] = *(const bf16x8*)&BsH[(wn + nt * 16 + l16) * 32 + quad * 8];
    }
#pragma unroll
    for (int nt = 0; nt < 4; nt++)
#pragma unroll
      for (int mt = 0; mt < 4; mt++) {
        acc[mt][nt] = MFMA16(afL[mt], bfL[nt], acc[mt][nt]);
        acc[mt][nt] = MFMA16(afH[mt], bfH[nt], acc[mt][nt]);
      }
  }

  const long po = (z == 0) ? offs.x : (z == 1) ? offs.y : (z == 2) ? offs.z : offs.w;
#pragma unroll
  for (int mt = 0; mt < 4; mt++)
#pragma unroll
    for (int nt = 0; nt < 4; nt++)
#pragma unroll
      for (int r = 0; r < 4; r++) {
        const int row = (int)bm + wm + mt * 16 + quad * 4 + r;
        const int col = (int)bn + wn + nt * 16 + l16;
        Pbase[po + (long)row * N + col] = (__bf16)acc[mt][nt][r];
      }
}

// ---------------------------------------------------------------------------
// Fused: sum 4 bf16 split-K partials + bias + residual, then LayerNorm.
// ---------------------------------------------------------------------------
template <int WB>
__global__ __launch_bounds__(256) void reduce_ln(
    const __bf16* __restrict__ Pbase, const long4 offs,
    const float* __restrict__ resid, const float* __restrict__ bias,
    const float* __restrict__ g, const float* __restrict__ be,
    float* __restrict__ outF, __bf16* __restrict__ outB) {
  const int tid = threadIdx.x;
  const long row = blockIdx.x;
  const int c = tid * 4;
  float4 v = ((const float4*)(resid + row * 1024))[tid];
  const float4 bb = ((const float4*)bias)[tid];
  v.x += bb.x; v.y += bb.y; v.z += bb.z; v.w += bb.w;
  const long lo[4] = {offs.x, offs.y, offs.z, offs.w};
#pragma unroll
  for (int s = 0; s < 4; s++) {
    const bf16x4 p = *(const bf16x4*)&Pbase[lo[s] + row * 1024 + c];
    v.x += (float)p[0]; v.y += (float)p[1]; v.z += (float)p[2]; v.w += (float)p[3];
  }
  float sum = v.x + v.y + v.z + v.w;
  float sq = v.x * v.x + v.y * v.y + v.z * v.z + v.w * v.w;
#pragma unroll
  for (int m = 32; m >= 1; m >>= 1) {
    sum += __shfl_xor(sum, m);
    sq += __shfl_xor(sq, m);
  }
  __shared__ float red[8];
  const int wave = tid >> 6;
  if ((tid & 63) == 0) {
    red[wave] = sum;
    red[4 + wave] = sq;
  }
  __syncthreads();
  sum = red[0] + red[1] + red[2] + red[3];
  sq = red[4] + red[5] + red[6] + red[7];
  const float mu = sum * (1.f / 1024.f);
  const float var = sq * (1.f / 1024.f) - mu * mu;
  const float rs = rsqrtf(var + 1e-5f);
  const float4 gv = ((const float4*)g)[tid];
  const float4 bv = ((const float4*)be)[tid];
  float4 o;
  o.x = (v.x - mu) * rs * gv.x + bv.x;
  o.y = (v.y - mu) * rs * gv.y + bv.y;
  o.z = (v.z - mu) * rs * gv.z + bv.z;
  o.w = (v.w - mu) * rs * gv.w + bv.w;
  ((float4*)(outF + row * 1024))[tid] = o;
  if (WB) {
    bf16x4 ob = {(__bf16)o.x, (__bf16)o.y, (__bf16)o.z, (__bf16)o.w};
    *(bf16x4*)&outB[row * 1024 + c] = ob;
  }
}

// ---------------------------------------------------------------------------
// Flash attention: LDS-staged K/V tiles, 32 q-rows/wave, XCD-swizzled grid,
// static softmax (exp2 domain). P buffer stride 68 (quad groups on distinct
// bank octets; reads via 8B-aligned b64 pairs).
// ---------------------------------------------------------------------------
__global__ __launch_bounds__(256) void flash_attn(const __bf16* __restrict__ Qb,
                                                  const __bf16* __restrict__ Kb,
                                                  const __bf16* __restrict__ Vtb,
                                                  __bf16* __restrict__ ctx) {
  __shared__ __bf16 KsLo[64 * 32], KsHi[64 * 32];   // K tile, d 0:32 / 32:64
  __shared__ __bf16 VsLo[64 * 32], VsHi[64 * 32];   // V^T tile, key 0:32 / 32:64
  __shared__ __bf16 Pb[4][32 * 68];                 // per-wave P, stride 68
  const int tid = threadIdx.x;
  const int wave = tid >> 6, lane = tid & 63;
  const int quad = lane >> 4, l16 = lane & 15;
  const int n = blockIdx.x;
  const int hb = n & 31;          // same hb -> same (n mod 8) -> same XCD
  const int qblk = n >> 5;
  const int h = hb >> 1, b = hb & 1;
  const __bf16* Q = Qb + (long)hb * 131072;
  const __bf16* K = Kb + (long)hb * 131072;
  const __bf16* Vt = Vtb + (long)hb * 131072;   // [t][d][k'] tiles of 64x64
  const int qr = qblk * 128 + wave * 32;

  bf16x8 q0[2], q1[2];
#pragma unroll
  for (int rb = 0; rb < 2; rb++) {
    q0[rb] = *(const bf16x8*)&Q[(qr + rb * 16 + l16) * 64 + quad * 8];
    q1[rb] = *(const bf16x8*)&Q[(qr + rb * 16 + l16) * 64 + 32 + quad * 8];
  }

  f32x4 o[2][4] = {};
  f32x4 lp[2] = {};

  const int sr = tid >> 2;         // staging row 0..63
  const int sc = (tid & 3) * 8;    // staging col chunk

  for (int kt = 0; kt < 2048; kt += 64) {
    __syncthreads();
    gl16(&K[(kt + sr) * 64 + sc], &KsLo[tid * 8]);
    gl16(&K[(kt + sr) * 64 + 32 + sc], &KsHi[tid * 8]);
    const __bf16* Vtile = Vt + (long)(kt >> 6) * 4096;
    gl16(&Vtile[sr * 64 + sc], &VsLo[tid * 8]);
    gl16(&Vtile[sr * 64 + 32 + sc], &VsHi[tid * 8]);
    __syncthreads();

    // S = Q K^T in exp2 domain
    bf16x8 kf0[4], kf1[4];
#pragma unroll
    for (int nt = 0; nt < 4; nt++) {
      kf0[nt] = *(const bf16x8*)&KsLo[(nt * 16 + l16) * 32 + quad * 8];
      kf1[nt] = *(const bf16x8*)&KsHi[(nt * 16 + l16) * 32 + quad * 8];
    }
    f32x4 s[2][4];
#pragma unroll
    for (int rb = 0; rb < 2; rb++)
#pragma unroll
      for (int nt = 0; nt < 4; nt++) {
        f32x4 z = {};
        z = MFMA16(q0[rb], kf0[nt], z);
        z = MFMA16(q1[rb], kf1[nt], z);
        s[rb][nt] = z;
      }

    // P = exp2(S); per-lane partial row sums
#pragma unroll
    for (int rb = 0; rb < 2; rb++)
#pragma unroll
      for (int nt = 0; nt < 4; nt++)
#pragma unroll
        for (int r = 0; r < 4; r++) {
          const float p = __builtin_amdgcn_exp2f(s[rb][nt][r]);
          s[rb][nt][r] = p;
          lp[rb][r] += p;
        }

    // P: C-layout -> LDS (stride 68) -> A-operand layout (wave-private)
#pragma unroll
    for (int rb = 0; rb < 2; rb++)
#pragma unroll
      for (int nt = 0; nt < 4; nt++)
#pragma unroll
        for (int r = 0; r < 4; r++)
          Pb[wave][(rb * 16 + quad * 4 + r) * 68 + nt * 16 + l16] =
              (__bf16)s[rb][nt][r];

    bf16x8 vf0[4], vf1[4];
#pragma unroll
    for (int nt = 0; nt < 4; nt++) {
      vf0[nt] = *(const bf16x8*)&VsLo[(nt * 16 + l16) * 32 + quad * 8];
      vf1[nt] = *(const bf16x8*)&VsHi[(nt * 16 + l16) * 32 + quad * 8];
    }
#pragma unroll
    for (int rb = 0; rb < 2; rb++) {
      const int pbase = (rb * 16 + l16) * 68;
      const bf16x4 pa0 = *(const bf16x4*)&Pb[wave][pbase + quad * 8];
      const bf16x4 pa1 = *(const bf16x4*)&Pb[wave][pbase + quad * 8 + 4];
      const bf16x4 pb0 = *(const bf16x4*)&Pb[wave][pbase + 32 + quad * 8];
      const bf16x4 pb1 = *(const bf16x4*)&Pb[wave][pbase + 32 + quad * 8 + 4];
      const bf16x8 p0 = __builtin_shufflevector(pa0, pa1, 0, 1, 2, 3, 4, 5, 6, 7);
      const bf16x8 p1 = __builtin_shufflevector(pb0, pb1, 0, 1, 2, 3, 4, 5, 6, 7);
#pragma unroll
      for (int nt = 0; nt < 4; nt++) {
        o[rb][nt] = MFMA16(p0, vf0[nt], o[rb][nt]);
        o[rb][nt] = MFMA16(p1, vf1[nt], o[rb][nt]);
      }
    }
  }

  // final row-sum reduction + ctx write in [b][s][h*64+d] layout
#pragma unroll
  for (int rb = 0; rb < 2; rb++) {
    float inv[4];
#pragma unroll
    for (int r = 0; r < 4; r++) {
      float l = lp[rb][r];
      l += __shfl_xor(l, 1);
      l += __shfl_xor(l, 2);
      l += __shfl_xor(l, 4);
      l += __shfl_xor(l, 8);
      inv[r] = __builtin_amdgcn_rcpf(l);
    }
#pragma unroll
    for (int nt = 0; nt < 4; nt++)
#pragma unroll
      for (int r = 0; r < 4; r++) {
        const int srow = qr + rb * 16 + quad * 4 + r;
        const float val = o[rb][nt][r] * inv[r];
        const int d = nt * 16 + l16;
        ctx[((long)(b * 2048 + srow)) * 1024 + h * 64 + d] = (__bf16)val;
      }
  }
}

// ---------------------------------------------------------------------------
extern "C" void kernel_launch(void* const* d_in, const int* in_sizes, int n_in,
                              void* d_out, int out_size, void* d_ws, size_t ws_size,
                              hipStream_t stream) {
  const float* x     = (const float*)d_in[0];
  const float* w_qkv = (const float*)d_in[1];
  const float* b_qkv = (const float*)d_in[2];
  const float* w_out = (const float*)d_in[3];
  const float* b_out = (const float*)d_in[4];
  const float* g1    = (const float*)d_in[5];
  const float* be1   = (const float*)d_in[6];
  const float* g2    = (const float*)d_in[7];
  const float* be2   = (const float*)d_in[8];
  const float* w1    = (const float*)d_in[9];
  const float* bf1   = (const float*)d_in[10];
  const float* w2    = (const float*)d_in[11];
  const float* bf2   = (const float*)d_in[12];
  float* out = (float*)d_out;

  // ---- workspace layout (MB offsets), 88 MB, lifetime-checked (round 6) ----
  //  0- 6 wqkvb | 6- 8 woutb | 8-16 w1b | 16-24 w2b | 24-32 xb
  // 32-56 qkvb | 56-64 ctxb | 64-80 res1 (f32) | 80-88 x1b
  // P1 (out-proj partials, 4x8 MB): {24,32,40,48}   (xb,qkvb dead)
  // hb (FFN1 out, 32 MB): 24-56                      (P1 dead)
  // P2 (FFN2 partials, 4x8 MB): {0,8,56,80}          (wqkvb/woutb,w1b,ctxb,x1b dead)
  char* ws = (char*)d_ws;
  const long MB = 1024L * 1024;
  __bf16* wsb   = (__bf16*)ws;
  __bf16* wqkvb = (__bf16*)(ws + 0 * MB);
  __bf16* woutb = (__bf16*)(ws + 6 * MB);
  __bf16* w1b   = (__bf16*)(ws + 8 * MB);
  __bf16* w2b   = (__bf16*)(ws + 16 * MB);
  __bf16* xb    = (__bf16*)(ws + 24 * MB);
  __bf16* qkvb  = (__bf16*)(ws + 32 * MB);
  __bf16* ctxb  = (__bf16*)(ws + 56 * MB);
  float*  res1  = (float*)(ws + 64 * MB);
  __bf16* x1b   = (__bf16*)(ws + 80 * MB);
  __bf16* hb    = (__bf16*)(ws + 24 * MB);

  const long4 offs_op = {24 * 524288L, 32 * 524288L, 40 * 524288L, 48 * 524288L};
  const long4 offs_f2 = {0 * 524288L, 8 * 524288L, 56 * 524288L, 80 * 524288L};

  // fused bf16 casts (16M elements)
  cast_all<<<16384, 256, 0, stream>>>(x, w_qkv, w_out, w1, w2,
                                      xb, wqkvb, woutb, w1b, w2b);

  // QKV projection (128x128, BK=64) -> q, k, tile-blocked V^T
  gemm_bt<0><<<dim3(24, 32), 256, 0, stream>>>(xb, wqkvb, b_qkv, qkvb,
                                               4096, 3072, 1024);
  // attention
  flash_attn<<<512, 256, 0, stream>>>(qkvb, qkvb + 4194304,
                                      qkvb + 2 * 4194304, ctxb);
  // out projection, split-K=4 (K=1024 -> 4x256, BK=64)
  gemm_split<<<dim3(8, 32, 4), 256, 0, stream>>>(ctxb, woutb, wsb, offs_op,
                                                 1024, 1024, 256);
  // fused: sum partials + b_out + x, LN1 -> res1 fp32 + x1b bf16
  reduce_ln<1><<<4096, 256, 0, stream>>>(wsb, offs_op, x, b_out, g1, be1,
                                         res1, x1b);
  // FFN1 + exact GELU (128x128, BK=64)
  gemm_bt<2><<<dim3(32, 32), 256, 0, stream>>>(x1b, w1b, bf1, hb,
                                               4096, 4096, 1024);
  // FFN2, split-K=4 (K=4096 -> 4x1024, BK=64)
  gemm_split<<<dim3(8, 32, 4), 256, 0, stream>>>(hb, w2b, wsb, offs_f2,
                                                 1024, 4096, 1024);
  // fused: sum partials + bf2 + res1, LN2 -> out
  reduce_ln<0><<<4096, 256, 0, stream>>>(wsb, offs_f2, res1, bf2, g2, be2,
                                         out, nullptr);
}